// Round 1
// baseline (354.503 us; speedup 1.0000x reference)
//
#include <hip/hip_runtime.h>
#include <stdint.h>

using u64 = unsigned long long;

constexpr int B_ = 2;
constexpr int NC = 512;
constexpr int NF = 8192;
constexpr int MT = 8192;

constexpr int TPB  = 256;
constexpr int RPT  = 4;            // rows per thread
constexpr int RPB  = TPB * RPT;    // rows per block = 1024
constexpr int TILE = 256;

#define DEVINL __device__ __forceinline__

DEVINL float fmulrn(float a, float b){ return __fmul_rn(a,b); }
DEVINL float faddrn(float a, float b){ return __fadd_rn(a,b); }
DEVINL float fsubrn(float a, float b){ return __fsub_rn(a,b); }

// Generic pairwise-min kernel.
// P: (B, nP, 3) "thread" points (one row per thread slot)
// Q: (B, nQ, 3) "tile" points (staged through LDS)
// minpack[b*nP + row] <- min over j of pack(d(row,j), j), d computed with the
// exact numpy fp32 arithmetic: d = max(((xx+yy) - 2*((x0y0+x1y1)+x2y2)), 0).
// Unsigned u64 min == (min d, then min j)  => np.argmin first-occurrence.
__global__ __launch_bounds__(TPB) void pairmin_kernel(
    const float* __restrict__ P, const float* __restrict__ Q,
    int nP, int nQ, int chunks, u64* __restrict__ minpack)
{
    __shared__ float4 tile[TILE];
    const int b        = blockIdx.z;
    const int row_base = blockIdx.y * RPB;
    const int cj       = (nQ + chunks - 1) / chunks;
    const int j0       = blockIdx.x * cj;
    const int j1       = min(nQ, j0 + cj);
    const int tid      = threadIdx.x;

    float x0[RPT], x1[RPT], x2[RPT], xx[RPT], dbest[RPT];
    int   jbest[RPT], rows[RPT];
    #pragma unroll
    for (int r = 0; r < RPT; ++r) {
        int row = row_base + tid + r * TPB;
        rows[r] = row;
        if (row < nP) {
            const float* p = P + ((size_t)b * nP + row) * 3;
            x0[r] = p[0]; x1[r] = p[1]; x2[r] = p[2];
            xx[r] = faddrn(faddrn(fmulrn(x0[r],x0[r]), fmulrn(x1[r],x1[r])),
                           fmulrn(x2[r],x2[r]));
        } else {
            x0[r] = x1[r] = x2[r] = xx[r] = 0.f;
        }
        dbest[r] = __int_as_float(0x7f7fffff);  // FLT_MAX
        jbest[r] = 0;
    }

    for (int tb = j0; tb < j1; tb += TILE) {
        int n = min(TILE, j1 - tb);
        __syncthreads();
        if (tid < n) {
            const float* q = Q + ((size_t)b * nQ + tb + tid) * 3;
            float q0 = q[0], q1 = q[1], q2 = q[2];
            float qq = faddrn(faddrn(fmulrn(q0,q0), fmulrn(q1,q1)), fmulrn(q2,q2));
            tile[tid] = make_float4(q0, q1, q2, qq);
        }
        __syncthreads();
        for (int jj = 0; jj < n; ++jj) {
            float4 q = tile[jj];
            int j = tb + jj;
            #pragma unroll
            for (int r = 0; r < RPT; ++r) {
                float xy = faddrn(faddrn(fmulrn(x0[r], q.x), fmulrn(x1[r], q.y)),
                                  fmulrn(x2[r], q.z));
                float t  = faddrn(xx[r], q.w);
                float d  = fsubrn(t, fmulrn(2.0f, xy));
                d = fmaxf(d, 0.0f);
                bool c = d < dbest[r];           // strict: first index wins in-thread
                dbest[r] = c ? d : dbest[r];
                jbest[r] = c ? j : jbest[r];
            }
        }
    }
    #pragma unroll
    for (int r = 0; r < RPT; ++r) {
        if (rows[r] < nP) {
            u64 pack = ((u64)__float_as_uint(dbest[r]) << 32) | (u64)(unsigned)jbest[r];
            atomicMin(&minpack[(size_t)b * nP + rows[r]], pack);
        }
    }
}

// Fine rows: sqrt-sum for chamfer d1, knn gather -> new_target, plus per-point
// stats: ydiff^2 (loss_ref), z^2 sums per batch (loss_rot).
__global__ __launch_bounds__(TPB) void finalize_fine_rows(
    const u64* __restrict__ minpack, const float* __restrict__ src,
    const float* __restrict__ tgt, float* __restrict__ new_tgt,
    double* __restrict__ acc)
{
    int i = blockIdx.x * TPB + threadIdx.x;   // 0 .. B*NF-1, block spans one b
    int b = i / NF;
    u64 p = minpack[i];
    float d1 = __uint_as_float((unsigned)(p >> 32));
    int idx  = (int)(p & 0xffffffffULL);
    float s = sqrtf(fmaxf(d1, 1e-12f));
    const float* y = tgt + ((size_t)b * MT + idx) * 3;
    float y0 = y[0], y1 = y[1], y2 = y[2];
    new_tgt[(size_t)i*3 + 0] = y0;
    new_tgt[(size_t)i*3 + 1] = y1;
    new_tgt[(size_t)i*3 + 2] = y2;
    float sy = src[(size_t)i*3 + 1];
    float sz = src[(size_t)i*3 + 2];
    float yd = sy - y1;
    float v_s = s, v_yd2 = yd*yd, v_zs = sz*sz, v_zt = y2*y2;
    for (int o = 32; o; o >>= 1) {
        v_s   += __shfl_down(v_s,   o);
        v_yd2 += __shfl_down(v_yd2, o);
        v_zs  += __shfl_down(v_zs,  o);
        v_zt  += __shfl_down(v_zt,  o);
    }
    if ((threadIdx.x & 63) == 0) {
        atomicAdd(&acc[0],     (double)v_s);
        atomicAdd(&acc[4],     (double)v_yd2);
        atomicAdd(&acc[5 + b], (double)v_zs);
        atomicAdd(&acc[7 + b], (double)v_zt);
    }
}

// Value-only finalize: sum of sqrt(max(dmin, eps)) into one accumulator slot.
__global__ __launch_bounds__(TPB) void finalize_min_sum(
    const u64* __restrict__ minpack, int count, double* __restrict__ slot)
{
    int i = blockIdx.x * TPB + threadIdx.x;
    float s = 0.f;
    if (i < count) {
        float d = __uint_as_float((unsigned)(minpack[i] >> 32));
        s = sqrtf(fmaxf(d, 1e-12f));
    }
    for (int o = 32; o; o >>= 1) s += __shfl_down(s, o);
    if ((threadIdx.x & 63) == 0) atomicAdd(slot, (double)s);
}

// Wedge-product volume terms for src and new_target, double accumulation.
__global__ __launch_bounds__(TPB) void volume_kernel(
    const float* __restrict__ src, const float* __restrict__ nt,
    double* __restrict__ dV)
{
    int b = blockIdx.y;
    int i = blockIdx.x * TPB + threadIdx.x;   // term index 0 .. NF-3
    double vs = 0.0, vt = 0.0;
    if (i < NF - 2) {
        {
            const float* p = src + ((size_t)b * NF + i) * 3;
            float c0 = p[1]*p[5] - p[2]*p[4];
            float c1 = p[2]*p[3] - p[0]*p[5];
            float c2 = p[0]*p[4] - p[1]*p[3];
            vs = (double)(c0*p[6] + c1*p[7] + c2*p[8]);
        }
        {
            const float* p = nt + ((size_t)b * NF + i) * 3;
            float c0 = p[1]*p[5] - p[2]*p[4];
            float c1 = p[2]*p[3] - p[0]*p[5];
            float c2 = p[0]*p[4] - p[1]*p[3];
            vt = (double)(c0*p[6] + c1*p[7] + c2*p[8]);
        }
    }
    for (int o = 32; o; o >>= 1) { vs += __shfl_down(vs, o); vt += __shfl_down(vt, o); }
    if ((threadIdx.x & 63) == 0) {
        atomicAdd(&dV[2*b + 0], vs);
        atomicAdd(&dV[2*b + 1], vt);
    }
}

__global__ void combine_kernel(const double* __restrict__ acc,
                               const double* __restrict__ dV,
                               float* __restrict__ out)
{
    double m_d1f = acc[0] / (double)(B_ * NF);
    double m_d2f = acc[1] / (double)(B_ * MT);
    double m_d1c = acc[2] / (double)(B_ * NC);
    double m_d2c = acc[3] / (double)(B_ * MT);
    double loss_align_fine   = 0.5 * (m_d1f + m_d2f);
    double loss_align_coarse = 0.5 * (m_d1c + m_d2c);
    double loss_ref = acc[4] / (double)(B_ * NF);
    double loss_rot = 0.0, loss_geo = 0.0;
    for (int b = 0; b < B_; ++b) {
        double dn = sqrt(acc[5 + b]) - sqrt(acc[7 + b]);
        loss_rot += dn * dn;
        double dv = (dV[2*b] - dV[2*b + 1]) / 6.0;
        loss_geo += dv * dv;
    }
    loss_rot /= (double)B_;
    loss_geo /= (double)B_;
    out[0] = (float)(loss_rot + loss_ref + loss_align_coarse + loss_align_fine + loss_geo);
}

extern "C" void kernel_launch(void* const* d_in, const int* in_sizes, int n_in,
                              void* d_out, int out_size, void* d_ws, size_t ws_size,
                              hipStream_t stream)
{
    const float* src_coarse = (const float*)d_in[0];
    const float* src_fine   = (const float*)d_in[1];
    const float* tgt        = (const float*)d_in[2];
    float* out = (float*)d_out;
    char*  ws  = (char*)d_ws;

    // ws layout (bytes):
    //   [0,       131072)  u64 mp_f_rows [B*NF]
    //   [131072,  262144)  u64 mp_f_cols [B*MT]
    //   [262144,  270336)  u64 mp_c_rows [B*NC]
    //   [270336,  401408)  u64 mp_c_cols [B*MT]
    //   [401408,  401440)  double dV[4]        (V_src[b], V_tgt[b])
    //   [401440,  401568)  double acc[16]
    //   [401568,  598176)  float new_target [B*NF*3]
    u64*    mp_f_rows = (u64*)(ws);
    u64*    mp_f_cols = (u64*)(ws + 131072);
    u64*    mp_c_rows = (u64*)(ws + 262144);
    u64*    mp_c_cols = (u64*)(ws + 270336);
    double* dV        = (double*)(ws + 401408);
    double* acc       = (double*)(ws + 401440);
    float*  new_tgt   = (float*)(ws + 401568);

    hipMemsetAsync(ws, 0xFF, 401408, stream);          // min sentinels
    hipMemsetAsync(ws + 401408, 0, 160, stream);       // dV + acc = 0

    // fine <-> target (both directions), coarse <-> target (both directions)
    pairmin_kernel<<<dim3(32, NF/RPB, B_), TPB, 0, stream>>>(src_fine, tgt, NF, MT, 32, mp_f_rows);
    pairmin_kernel<<<dim3(32, MT/RPB, B_), TPB, 0, stream>>>(tgt, src_fine, MT, NF, 32, mp_f_cols);
    pairmin_kernel<<<dim3(8,  1,      B_), TPB, 0, stream>>>(src_coarse, tgt, NC, MT, 8, mp_c_rows);
    pairmin_kernel<<<dim3(2,  MT/RPB, B_), TPB, 0, stream>>>(tgt, src_coarse, MT, NC, 2, mp_c_cols);

    finalize_fine_rows<<<dim3(B_*NF/TPB), TPB, 0, stream>>>(mp_f_rows, src_fine, tgt, new_tgt, acc);
    finalize_min_sum<<<dim3(B_*MT/TPB), TPB, 0, stream>>>(mp_f_cols, B_*MT, acc + 1);
    finalize_min_sum<<<dim3(B_*NC/TPB), TPB, 0, stream>>>(mp_c_rows, B_*NC, acc + 2);
    finalize_min_sum<<<dim3(B_*MT/TPB), TPB, 0, stream>>>(mp_c_cols, B_*MT, acc + 3);

    volume_kernel<<<dim3((NF - 2 + TPB - 1)/TPB, B_), TPB, 0, stream>>>(src_fine, new_tgt, dV);

    combine_kernel<<<1, 1, 0, stream>>>(acc, dV, out);
}

// Round 2
// 203.396 us; speedup vs baseline: 1.7429x; 1.7429x over previous
//
#include <hip/hip_runtime.h>
#include <stdint.h>

using u64 = unsigned long long;

constexpr int B_ = 2;
constexpr int NC = 512;
constexpr int NF = 8192;
constexpr int MT = 8192;

constexpr int TPB  = 256;
constexpr int RPT  = 2;            // rows per thread
constexpr int RPB  = TPB * RPT;    // rows per block = 512
constexpr int TILE = 256;

#define DEVINL __device__ __forceinline__

DEVINL float fmulrn(float a, float b){ return __fmul_rn(a,b); }
DEVINL float faddrn(float a, float b){ return __fadd_rn(a,b); }
DEVINL float fsubrn(float a, float b){ return __fsub_rn(a,b); }

// Generic pairwise-min kernel.
// P: (B, nP, 3) "thread" points (RPT rows per thread)
// Q: (B, nQ, 3) "tile" points (staged through LDS)
// minpack[b*nP + row] <- min over j of pack(d(row,j), j), d computed with the
// exact numpy fp32 arithmetic: d = max(((xx+yy) - 2*((x0y0+x1y1)+x2y2)), 0).
// Unsigned u64 min == (min d, then min j)  => np.argmin first-occurrence.
// __launch_bounds__(256,4): 4 waves/EU -> 16 waves/CU with 4 blocks/CU.
__global__ __launch_bounds__(TPB, 4) void pairmin_kernel(
    const float* __restrict__ P, const float* __restrict__ Q,
    int nP, int nQ, int chunks, u64* __restrict__ minpack)
{
    __shared__ float4 tile[TILE];
    const int b        = blockIdx.z;
    const int row_base = blockIdx.y * RPB;
    const int cj       = (nQ + chunks - 1) / chunks;
    const int j0       = blockIdx.x * cj;
    const int j1       = min(nQ, j0 + cj);
    const int tid      = threadIdx.x;

    float x0[RPT], x1[RPT], x2[RPT], xx[RPT], dbest[RPT];
    int   jbest[RPT], rows[RPT];
    #pragma unroll
    for (int r = 0; r < RPT; ++r) {
        int row = row_base + tid + r * TPB;
        rows[r] = row;
        if (row < nP) {
            const float* p = P + ((size_t)b * nP + row) * 3;
            x0[r] = p[0]; x1[r] = p[1]; x2[r] = p[2];
            xx[r] = faddrn(faddrn(fmulrn(x0[r],x0[r]), fmulrn(x1[r],x1[r])),
                           fmulrn(x2[r],x2[r]));
        } else {
            x0[r] = x1[r] = x2[r] = xx[r] = 0.f;
        }
        dbest[r] = __int_as_float(0x7f7fffff);  // FLT_MAX
        jbest[r] = 0;
    }

    for (int tb = j0; tb < j1; tb += TILE) {
        int n = min(TILE, j1 - tb);
        __syncthreads();
        if (tid < n) {
            const float* q = Q + ((size_t)b * nQ + tb + tid) * 3;
            float q0 = q[0], q1 = q[1], q2 = q[2];
            float qq = faddrn(faddrn(fmulrn(q0,q0), fmulrn(q1,q1)), fmulrn(q2,q2));
            tile[tid] = make_float4(q0, q1, q2, qq);
        }
        __syncthreads();

        int jj = 0;
        // Unrolled by 4: group the 4 ds_read_b128 so they pipeline (one
        // waitcnt covers all), instead of a 120-cyc serial stall per j.
        for (; jj + 4 <= n; jj += 4) {
            float4 qv[4];
            #pragma unroll
            for (int u = 0; u < 4; ++u) qv[u] = tile[jj + u];
            #pragma unroll
            for (int u = 0; u < 4; ++u) {
                float4 q = qv[u];
                int j = tb + jj + u;
                #pragma unroll
                for (int r = 0; r < RPT; ++r) {
                    float xy = faddrn(faddrn(fmulrn(x0[r], q.x), fmulrn(x1[r], q.y)),
                                      fmulrn(x2[r], q.z));
                    float t  = faddrn(xx[r], q.w);
                    float d  = fsubrn(t, fmulrn(2.0f, xy));
                    d = fmaxf(d, 0.0f);
                    bool c = d < dbest[r];       // strict: first index wins
                    dbest[r] = c ? d : dbest[r];
                    jbest[r] = c ? j : jbest[r];
                }
            }
        }
        for (; jj < n; ++jj) {                   // remainder (unused for our sizes)
            float4 q = tile[jj];
            int j = tb + jj;
            #pragma unroll
            for (int r = 0; r < RPT; ++r) {
                float xy = faddrn(faddrn(fmulrn(x0[r], q.x), fmulrn(x1[r], q.y)),
                                  fmulrn(x2[r], q.z));
                float t  = faddrn(xx[r], q.w);
                float d  = fsubrn(t, fmulrn(2.0f, xy));
                d = fmaxf(d, 0.0f);
                bool c = d < dbest[r];
                dbest[r] = c ? d : dbest[r];
                jbest[r] = c ? j : jbest[r];
            }
        }
    }
    #pragma unroll
    for (int r = 0; r < RPT; ++r) {
        if (rows[r] < nP) {
            u64 pack = ((u64)__float_as_uint(dbest[r]) << 32) | (u64)(unsigned)jbest[r];
            atomicMin(&minpack[(size_t)b * nP + rows[r]], pack);
        }
    }
}

// Fine rows: sqrt-sum for chamfer d1, knn gather -> new_target, plus per-point
// stats: ydiff^2 (loss_ref), z^2 sums per batch (loss_rot).
__global__ __launch_bounds__(TPB) void finalize_fine_rows(
    const u64* __restrict__ minpack, const float* __restrict__ src,
    const float* __restrict__ tgt, float* __restrict__ new_tgt,
    double* __restrict__ acc)
{
    int i = blockIdx.x * TPB + threadIdx.x;   // 0 .. B*NF-1, block spans one b
    int b = i / NF;
    u64 p = minpack[i];
    float d1 = __uint_as_float((unsigned)(p >> 32));
    int idx  = (int)(p & 0xffffffffULL);
    float s = sqrtf(fmaxf(d1, 1e-12f));
    const float* y = tgt + ((size_t)b * MT + idx) * 3;
    float y0 = y[0], y1 = y[1], y2 = y[2];
    new_tgt[(size_t)i*3 + 0] = y0;
    new_tgt[(size_t)i*3 + 1] = y1;
    new_tgt[(size_t)i*3 + 2] = y2;
    float sy = src[(size_t)i*3 + 1];
    float sz = src[(size_t)i*3 + 2];
    float yd = sy - y1;
    float v_s = s, v_yd2 = yd*yd, v_zs = sz*sz, v_zt = y2*y2;
    for (int o = 32; o; o >>= 1) {
        v_s   += __shfl_down(v_s,   o);
        v_yd2 += __shfl_down(v_yd2, o);
        v_zs  += __shfl_down(v_zs,  o);
        v_zt  += __shfl_down(v_zt,  o);
    }
    if ((threadIdx.x & 63) == 0) {
        atomicAdd(&acc[0],     (double)v_s);
        atomicAdd(&acc[4],     (double)v_yd2);
        atomicAdd(&acc[5 + b], (double)v_zs);
        atomicAdd(&acc[7 + b], (double)v_zt);
    }
}

// Value-only finalize: sum of sqrt(max(dmin, eps)) into one accumulator slot.
__global__ __launch_bounds__(TPB) void finalize_min_sum(
    const u64* __restrict__ minpack, int count, double* __restrict__ slot)
{
    int i = blockIdx.x * TPB + threadIdx.x;
    float s = 0.f;
    if (i < count) {
        float d = __uint_as_float((unsigned)(minpack[i] >> 32));
        s = sqrtf(fmaxf(d, 1e-12f));
    }
    for (int o = 32; o; o >>= 1) s += __shfl_down(s, o);
    if ((threadIdx.x & 63) == 0) atomicAdd(slot, (double)s);
}

// Wedge-product volume terms for src and new_target, double accumulation.
__global__ __launch_bounds__(TPB) void volume_kernel(
    const float* __restrict__ src, const float* __restrict__ nt,
    double* __restrict__ dV)
{
    int b = blockIdx.y;
    int i = blockIdx.x * TPB + threadIdx.x;   // term index 0 .. NF-3
    double vs = 0.0, vt = 0.0;
    if (i < NF - 2) {
        {
            const float* p = src + ((size_t)b * NF + i) * 3;
            float c0 = p[1]*p[5] - p[2]*p[4];
            float c1 = p[2]*p[3] - p[0]*p[5];
            float c2 = p[0]*p[4] - p[1]*p[3];
            vs = (double)(c0*p[6] + c1*p[7] + c2*p[8]);
        }
        {
            const float* p = nt + ((size_t)b * NF + i) * 3;
            float c0 = p[1]*p[5] - p[2]*p[4];
            float c1 = p[2]*p[3] - p[0]*p[5];
            float c2 = p[0]*p[4] - p[1]*p[3];
            vt = (double)(c0*p[6] + c1*p[7] + c2*p[8]);
        }
    }
    for (int o = 32; o; o >>= 1) { vs += __shfl_down(vs, o); vt += __shfl_down(vt, o); }
    if ((threadIdx.x & 63) == 0) {
        atomicAdd(&dV[2*b + 0], vs);
        atomicAdd(&dV[2*b + 1], vt);
    }
}

__global__ void combine_kernel(const double* __restrict__ acc,
                               const double* __restrict__ dV,
                               float* __restrict__ out)
{
    double m_d1f = acc[0] / (double)(B_ * NF);
    double m_d2f = acc[1] / (double)(B_ * MT);
    double m_d1c = acc[2] / (double)(B_ * NC);
    double m_d2c = acc[3] / (double)(B_ * MT);
    double loss_align_fine   = 0.5 * (m_d1f + m_d2f);
    double loss_align_coarse = 0.5 * (m_d1c + m_d2c);
    double loss_ref = acc[4] / (double)(B_ * NF);
    double loss_rot = 0.0, loss_geo = 0.0;
    for (int b = 0; b < B_; ++b) {
        double dn = sqrt(acc[5 + b]) - sqrt(acc[7 + b]);
        loss_rot += dn * dn;
        double dv = (dV[2*b] - dV[2*b + 1]) / 6.0;
        loss_geo += dv * dv;
    }
    loss_rot /= (double)B_;
    loss_geo /= (double)B_;
    out[0] = (float)(loss_rot + loss_ref + loss_align_coarse + loss_align_fine + loss_geo);
}

extern "C" void kernel_launch(void* const* d_in, const int* in_sizes, int n_in,
                              void* d_out, int out_size, void* d_ws, size_t ws_size,
                              hipStream_t stream)
{
    const float* src_coarse = (const float*)d_in[0];
    const float* src_fine   = (const float*)d_in[1];
    const float* tgt        = (const float*)d_in[2];
    float* out = (float*)d_out;
    char*  ws  = (char*)d_ws;

    // ws layout (bytes):
    //   [0,       131072)  u64 mp_f_rows [B*NF]
    //   [131072,  262144)  u64 mp_f_cols [B*MT]
    //   [262144,  270336)  u64 mp_c_rows [B*NC]
    //   [270336,  401408)  u64 mp_c_cols [B*MT]
    //   [401408,  401440)  double dV[4]        (V_src[b], V_tgt[b])
    //   [401440,  401568)  double acc[16]
    //   [401568,  598176)  float new_target [B*NF*3]
    u64*    mp_f_rows = (u64*)(ws);
    u64*    mp_f_cols = (u64*)(ws + 131072);
    u64*    mp_c_rows = (u64*)(ws + 262144);
    u64*    mp_c_cols = (u64*)(ws + 270336);
    double* dV        = (double*)(ws + 401408);
    double* acc       = (double*)(ws + 401440);
    float*  new_tgt   = (float*)(ws + 401568);

    hipMemsetAsync(ws, 0xFF, 401408, stream);          // min sentinels
    hipMemsetAsync(ws + 401408, 0, 160, stream);       // dV + acc = 0

    // fine <-> target (both directions), coarse <-> target (both directions)
    // RPB=512: fine grids are 1024 blocks -> 4 blocks/CU -> 16 waves/CU.
    pairmin_kernel<<<dim3(32, NF/RPB, B_), TPB, 0, stream>>>(src_fine, tgt, NF, MT, 32, mp_f_rows);
    pairmin_kernel<<<dim3(32, MT/RPB, B_), TPB, 0, stream>>>(tgt, src_fine, MT, NF, 32, mp_f_cols);
    pairmin_kernel<<<dim3(32, 1,      B_), TPB, 0, stream>>>(src_coarse, tgt, NC, MT, 32, mp_c_rows);
    pairmin_kernel<<<dim3(2,  MT/RPB, B_), TPB, 0, stream>>>(tgt, src_coarse, MT, NC, 2, mp_c_cols);

    finalize_fine_rows<<<dim3(B_*NF/TPB), TPB, 0, stream>>>(mp_f_rows, src_fine, tgt, new_tgt, acc);
    finalize_min_sum<<<dim3(B_*MT/TPB), TPB, 0, stream>>>(mp_f_cols, B_*MT, acc + 1);
    finalize_min_sum<<<dim3(B_*NC/TPB), TPB, 0, stream>>>(mp_c_rows, B_*NC, acc + 2);
    finalize_min_sum<<<dim3(B_*MT/TPB), TPB, 0, stream>>>(mp_c_cols, B_*MT, acc + 3);

    volume_kernel<<<dim3((NF - 2 + TPB - 1)/TPB, B_), TPB, 0, stream>>>(src_fine, new_tgt, dV);

    combine_kernel<<<1, 1, 0, stream>>>(acc, dV, out);
}

// Round 3
// 143.185 us; speedup vs baseline: 2.4758x; 1.4205x over previous
//
#include <hip/hip_runtime.h>
#include <stdint.h>

using u64 = unsigned long long;

constexpr int B_ = 2;
constexpr int NC = 512;
constexpr int NF = 8192;
constexpr int MT = 8192;

constexpr int TPB  = 256;
constexpr int RPT  = 2;            // rows per thread
constexpr int RPB  = TPB * RPT;    // rows per block = 512
constexpr int TILE = 256;          // j-chunk per block (every role uses exactly one tile)

#define DEVINL __device__ __forceinline__

DEVINL float fmulrn(float a, float b){ return __fmul_rn(a,b); }
DEVINL float faddrn(float a, float b){ return __fadd_rn(a,b); }
DEVINL float fsubrn(float a, float b){ return __fsub_rn(a,b); }

// Core pairwise-min body. Each block: RPB rows of P vs one TILE-sized chunk of Q.
// d computed with the exact numpy fp32 arithmetic:
//   d = max(((xx+qq) - 2*((x0q0+x1q1)+x2q2)), 0)
// ARGMIN=true : track (d,j) packed u64, first-index tie-break -> atomicMin u64.
// ARGMIN=false: value only, v_med3(d,0,dbest) fuses clamp+min (bit-identical),
//               9 VALU/pair instead of 12 -> atomicMin on float bits (d>=0 monotone).
template<bool ARGMIN>
DEVINL void pairmin_body(const float* __restrict__ P, const float* __restrict__ Q,
                         int nP, int nQ, int b, int row_base, int j0,
                         u64* __restrict__ outPack, unsigned* __restrict__ outVal,
                         float4* tile)
{
    const int tid = threadIdx.x;
    float x0[RPT], x1[RPT], x2[RPT], xx[RPT], dbest[RPT];
    int jbest[RPT];
    #pragma unroll
    for (int r = 0; r < RPT; ++r) {
        int row = row_base + tid + r * TPB;         // shapes divide exactly, no guard
        const float* p = P + ((size_t)b * nP + row) * 3;
        x0[r] = p[0]; x1[r] = p[1]; x2[r] = p[2];
        xx[r] = faddrn(faddrn(fmulrn(x0[r],x0[r]), fmulrn(x1[r],x1[r])),
                       fmulrn(x2[r],x2[r]));
        dbest[r] = __int_as_float(0x7f7fffff);      // FLT_MAX
        jbest[r] = 0;
    }
    {   // stage one TILE of Q (with qq) into LDS
        const float* q = Q + ((size_t)b * nQ + j0 + tid) * 3;
        float q0 = q[0], q1 = q[1], q2 = q[2];
        float qq = faddrn(faddrn(fmulrn(q0,q0), fmulrn(q1,q1)), fmulrn(q2,q2));
        tile[tid] = make_float4(q0, q1, q2, qq);
    }
    __syncthreads();

    for (int jj = 0; jj < TILE; jj += 4) {
        float4 qv[4];
        #pragma unroll
        for (int u = 0; u < 4; ++u) qv[u] = tile[jj + u];  // group ds_reads
        #pragma unroll
        for (int u = 0; u < 4; ++u) {
            float4 q = qv[u];
            #pragma unroll
            for (int r = 0; r < RPT; ++r) {
                float xy = faddrn(faddrn(fmulrn(x0[r], q.x), fmulrn(x1[r], q.y)),
                                  fmulrn(x2[r], q.z));
                float t  = faddrn(xx[r], q.w);
                float d  = fsubrn(t, fmulrn(2.0f, xy));
                if (ARGMIN) {
                    d = fmaxf(d, 0.0f);
                    bool c = d < dbest[r];          // strict: first index wins
                    dbest[r] = c ? d : dbest[r];
                    jbest[r] = c ? (j0 + jj + u) : jbest[r];
                } else {
                    // med3(d, 0, dbest) == min(dbest, max(d, 0)) for dbest>=0
                    dbest[r] = __builtin_amdgcn_fmed3f(d, 0.0f, dbest[r]);
                }
            }
        }
    }
    #pragma unroll
    for (int r = 0; r < RPT; ++r) {
        int row = row_base + tid + r * TPB;
        if (ARGMIN) {
            u64 pk = ((u64)__float_as_uint(dbest[r]) << 32) | (u64)(unsigned)jbest[r];
            atomicMin(&outPack[(size_t)b * nP + row], pk);
        } else {
            atomicMin(&outVal[(size_t)b * nP + row], __float_as_uint(dbest[r]));
        }
    }
}

// All four pairwise passes in ONE dispatch. Coarse roles first so their
// latency-bound 128 blocks overlap the fine work.
//  [0,   64)  coarse-rows : P=coarse(512), Q=tgt(8192), value-only
//  [64, 128)  coarse-cols : P=tgt(8192),  Q=coarse(512), value-only
//  [128,1152) fine-rows   : P=fine(8192), Q=tgt(8192),  ARGMIN
//  [1152,2176) fine-cols  : P=tgt(8192),  Q=fine(8192), value-only
__global__ __launch_bounds__(TPB, 4) void pairmin_all(
    const float* __restrict__ coarse, const float* __restrict__ fine,
    const float* __restrict__ tgt,
    u64* __restrict__ mp_f_rows, unsigned* __restrict__ val_f_cols,
    unsigned* __restrict__ val_c_rows, unsigned* __restrict__ val_c_cols)
{
    __shared__ float4 tile[TILE];
    int bx = blockIdx.x;
    if (bx < 64) {
        int chunk = bx & 31, b = bx >> 5;                       // 32 chunks x 2 b
        pairmin_body<false>(coarse, tgt, NC, MT, b, 0, chunk*TILE,
                            nullptr, val_c_rows, tile);
    } else if (bx < 128) {
        int i = bx - 64;
        int chunk = i & 1, yb = (i >> 1) & 15, b = i >> 5;      // 2 x 16 x 2
        pairmin_body<false>(tgt, coarse, MT, NC, b, yb*RPB, chunk*TILE,
                            nullptr, val_c_cols, tile);
    } else if (bx < 1152) {
        int i = bx - 128;
        int chunk = i & 31, yb = (i >> 5) & 15, b = i >> 9;     // 32 x 16 x 2
        pairmin_body<true>(fine, tgt, NF, MT, b, yb*RPB, chunk*TILE,
                           mp_f_rows, nullptr, tile);
    } else {
        int i = bx - 1152;
        int chunk = i & 31, yb = (i >> 5) & 15, b = i >> 9;
        pairmin_body<false>(tgt, fine, MT, NF, b, yb*RPB, chunk*TILE,
                            nullptr, val_f_cols, tile);
    }
}

// Fused fine-row finalize + wedge volumes: chamfer d1 sum, knn gather (to LDS,
// with 2-row halo), loss_ref / loss_rot stats, and volume terms for src and
// gathered target — all in one kernel. grid = (NF/TPB, B_).
__global__ __launch_bounds__(TPB) void finalize_fine(
    const u64* __restrict__ mp, const float* __restrict__ src,
    const float* __restrict__ tgt, double* __restrict__ acc,
    double* __restrict__ dV)
{
    __shared__ float sp[TPB + 2][3];
    __shared__ float yp[TPB + 2][3];
    const int b    = blockIdx.y;
    const int base = blockIdx.x * TPB;
    const int tid  = threadIdx.x;
    const int row  = base + tid;

    u64 p = mp[(size_t)b * NF + row];
    float d1 = __uint_as_float((unsigned)(p >> 32));
    int idx  = (int)(p & 0xffffffffULL);
    float s = sqrtf(fmaxf(d1, 1e-12f));
    const float* y  = tgt + ((size_t)b * MT + idx) * 3;
    const float* sr = src + ((size_t)b * NF + row) * 3;
    float y0 = y[0],  y1 = y[1],  y2 = y[2];
    float s0 = sr[0], s1 = sr[1], s2 = sr[2];
    yp[tid][0] = y0; yp[tid][1] = y1; yp[tid][2] = y2;
    sp[tid][0] = s0; sp[tid][1] = s1; sp[tid][2] = s2;
    if (tid < 2 && base + TPB + tid < NF) {      // halo rows
        int r2 = base + TPB + tid;
        u64 p2 = mp[(size_t)b * NF + r2];
        int i2 = (int)(p2 & 0xffffffffULL);
        const float* yh = tgt + ((size_t)b * MT + i2) * 3;
        const float* sh = src + ((size_t)b * NF + r2) * 3;
        #pragma unroll
        for (int k = 0; k < 3; ++k) { yp[TPB + tid][k] = yh[k]; sp[TPB + tid][k] = sh[k]; }
    }
    __syncthreads();

    float yd = s1 - y1;
    float v_s = s, v_yd2 = yd * yd, v_zs = s2 * s2, v_zt = y2 * y2;

    double vs = 0.0, vt = 0.0;
    if (row <= NF - 3) {     // same f32 expressions as the bit-matching R2 kernel
        {
            const float* a = sp[tid]; const float* c = sp[tid+1]; const float* e = sp[tid+2];
            float c0 = a[1]*c[2] - a[2]*c[1];
            float c1 = a[2]*c[0] - a[0]*c[2];
            float c2 = a[0]*c[1] - a[1]*c[0];
            vs = (double)(c0*e[0] + c1*e[1] + c2*e[2]);
        }
        {
            const float* a = yp[tid]; const float* c = yp[tid+1]; const float* e = yp[tid+2];
            float c0 = a[1]*c[2] - a[2]*c[1];
            float c1 = a[2]*c[0] - a[0]*c[2];
            float c2 = a[0]*c[1] - a[1]*c[0];
            vt = (double)(c0*e[0] + c1*e[1] + c2*e[2]);
        }
    }
    for (int o = 32; o; o >>= 1) {
        v_s   += __shfl_down(v_s,   o);
        v_yd2 += __shfl_down(v_yd2, o);
        v_zs  += __shfl_down(v_zs,  o);
        v_zt  += __shfl_down(v_zt,  o);
        vs    += __shfl_down(vs,    o);
        vt    += __shfl_down(vt,    o);
    }
    if ((tid & 63) == 0) {
        atomicAdd(&acc[0],     (double)v_s);
        atomicAdd(&acc[4],     (double)v_yd2);
        atomicAdd(&acc[5 + b], (double)v_zs);
        atomicAdd(&acc[7 + b], (double)v_zt);
        atomicAdd(&dV[2*b + 0], vs);
        atomicAdd(&dV[2*b + 1], vt);
    }
}

// The three value-only reductions in one kernel (ranges are 256-multiples,
// so the target slot is block-uniform).
__global__ __launch_bounds__(TPB) void finalize_vals(
    const unsigned* __restrict__ vf, const unsigned* __restrict__ vcr,
    const unsigned* __restrict__ vcc, double* __restrict__ acc)
{
    int g = blockIdx.x * TPB + threadIdx.x;
    const unsigned* a; int off; int slot;
    if (g < 16384)      { a = vf;  off = g;          slot = 1; }
    else if (g < 17408) { a = vcr; off = g - 16384;  slot = 2; }
    else                { a = vcc; off = g - 17408;  slot = 3; }
    float d = __uint_as_float(a[off]);
    float s = sqrtf(fmaxf(d, 1e-12f));
    for (int o = 32; o; o >>= 1) s += __shfl_down(s, o);
    if ((threadIdx.x & 63) == 0) atomicAdd(&acc[slot], (double)s);
}

__global__ void combine_kernel(const double* __restrict__ acc,
                               const double* __restrict__ dV,
                               float* __restrict__ out)
{
    double m_d1f = acc[0] / (double)(B_ * NF);
    double m_d2f = acc[1] / (double)(B_ * MT);
    double m_d1c = acc[2] / (double)(B_ * NC);
    double m_d2c = acc[3] / (double)(B_ * MT);
    double loss_align_fine   = 0.5 * (m_d1f + m_d2f);
    double loss_align_coarse = 0.5 * (m_d1c + m_d2c);
    double loss_ref = acc[4] / (double)(B_ * NF);
    double loss_rot = 0.0, loss_geo = 0.0;
    for (int b = 0; b < B_; ++b) {
        double dn = sqrt(acc[5 + b]) - sqrt(acc[7 + b]);
        loss_rot += dn * dn;
        double dv = (dV[2*b] - dV[2*b + 1]) / 6.0;
        loss_geo += dv * dv;
    }
    loss_rot /= (double)B_;
    loss_geo /= (double)B_;
    out[0] = (float)(loss_rot + loss_ref + loss_align_coarse + loss_align_fine + loss_geo);
}

extern "C" void kernel_launch(void* const* d_in, const int* in_sizes, int n_in,
                              void* d_out, int out_size, void* d_ws, size_t ws_size,
                              hipStream_t stream)
{
    const float* src_coarse = (const float*)d_in[0];
    const float* src_fine   = (const float*)d_in[1];
    const float* tgt        = (const float*)d_in[2];
    float* out = (float*)d_out;
    char*  ws  = (char*)d_ws;

    // ws layout (bytes):
    //   [0,      131072)  u64 mp_f_rows  [B*NF]   (d,j) packed
    //   [131072, 196608)  u32 val_f_cols [B*MT]
    //   [196608, 200704)  u32 val_c_rows [B*NC]
    //   [200704, 266240)  u32 val_c_cols [B*MT]
    //   [266240, 266272)  double dV[4]   (V_src[b], V_tgt[b])
    //   [266272, 266400)  double acc[16]
    u64*      mp_f_rows  = (u64*)(ws);
    unsigned* val_f_cols = (unsigned*)(ws + 131072);
    unsigned* val_c_rows = (unsigned*)(ws + 196608);
    unsigned* val_c_cols = (unsigned*)(ws + 200704);
    double*   dV         = (double*)(ws + 266240);
    double*   acc        = (double*)(ws + 266272);

    hipMemsetAsync(ws, 0xFF, 266240, stream);        // min sentinels
    hipMemsetAsync(ws + 266240, 0, 160, stream);     // dV + acc = 0

    pairmin_all<<<dim3(2176), TPB, 0, stream>>>(
        src_coarse, src_fine, tgt, mp_f_rows, val_f_cols, val_c_rows, val_c_cols);

    finalize_fine<<<dim3(NF / TPB, B_), TPB, 0, stream>>>(mp_f_rows, src_fine, tgt, acc, dV);
    finalize_vals<<<dim3(132), TPB, 0, stream>>>(val_f_cols, val_c_rows, val_c_cols, acc);
    combine_kernel<<<1, 1, 0, stream>>>(acc, dV, out);
}

// Round 4
// 130.302 us; speedup vs baseline: 2.7206x; 1.0989x over previous
//
#include <hip/hip_runtime.h>
#include <stdint.h>
#include <float.h>

using u64 = unsigned long long;
typedef float v2f __attribute__((ext_vector_type(2)));

constexpr int B_ = 2;
constexpr int NC = 512;
constexpr int NF = 8192;
constexpr int MT = 8192;

constexpr int TPB  = 256;
constexpr int RPB  = 512;          // rows per block (2 per thread, packed as v2f)
constexpr int TILE = 256;
constexpr int CF   = 16;           // fine chunks (j-split) -> 512 j per chunk
constexpr int TAIL_BLOCKS = 196;   // 64 fine-rows + 64 fine-cols + 4 coarse-rows + 64 coarse-cols

#define DEVINL __device__ __forceinline__

// ---------------------------------------------------------------------------
// pairmin: each block computes, for RPB rows of P, the min over its j-chunk of
//   d = max((xx+qq) - 2*xy, 0)
// computed bit-exactly vs numpy fp32:
//   2*xy is computed as ((2x0)q0 + (2x1)q1) + (2x2)q2  — power-of-2 scaling
//   commutes with round-to-nearest, so this equals 2*((x0q0+x1q1)+x2q2) exactly.
// Two rows per thread are packed in v2f so the compiler can emit v_pk_*_f32
// (two correctly-rounded fp32 ops per inst — bit-identical to scalar).
// Results go to per-chunk partial slots: NO atomics, NO sentinel init.
// ---------------------------------------------------------------------------
template<bool ARGMIN>
DEVINL void pairmin_body(const float* __restrict__ P, const float* __restrict__ Q,
                         int nP, int nQ, int b, int row_base, int j0, int ntiles,
                         int chunk, int nRowsTot,
                         u64* __restrict__ outPack, unsigned* __restrict__ outVal,
                         float4* tile)
{
#pragma clang fp contract(off)
    const int tid  = threadIdx.x;
    const int row0 = row_base + tid;
    const int row1 = row_base + tid + TPB;
    const float* p0 = P + ((size_t)b * nP + row0) * 3;
    const float* p1 = P + ((size_t)b * nP + row1) * 3;
    float a0 = p0[0], a1 = p0[1], a2 = p0[2];
    float e0 = p1[0], e1 = p1[1], e2 = p1[2];
    v2f tx0 = {2.0f * a0, 2.0f * e0};
    v2f tx1 = {2.0f * a1, 2.0f * e1};
    v2f tx2 = {2.0f * a2, 2.0f * e2};
    v2f txx = {(a0*a0 + a1*a1) + a2*a2, (e0*e0 + e1*e1) + e2*e2};
    v2f dbest = {FLT_MAX, FLT_MAX};
    const v2f vzero = {0.0f, 0.0f};
    int jb0 = 0, jb1 = 0;

    for (int t = 0; t < ntiles; ++t) {
        __syncthreads();
        {
            const float* q = Q + ((size_t)b * nQ + j0 + t * TILE + tid) * 3;
            float q0 = q[0], q1 = q[1], q2 = q[2];
            tile[tid] = make_float4(q0, q1, q2, (q0*q0 + q1*q1) + q2*q2);
        }
        __syncthreads();
        const int jbase = j0 + t * TILE;
        for (int jj = 0; jj < TILE; jj += 4) {
            float4 qv[4];
            #pragma unroll
            for (int u = 0; u < 4; ++u) qv[u] = tile[jj + u];   // grouped ds_reads
            #pragma unroll
            for (int u = 0; u < 4; ++u) {
                v2f s  = (tx0 * qv[u].x + tx1 * qv[u].y) + tx2 * qv[u].z;  // == 2*xy
                v2f tt = txx + qv[u].w;
                v2f d  = tt - s;
                v2f dc = __builtin_elementwise_max(d, vzero);
                if (ARGMIN) {
                    int j = jbase + jj + u;
                    bool c0 = dc.x < dbest.x;   // strict: first index wins
                    dbest.x = c0 ? dc.x : dbest.x;  jb0 = c0 ? j : jb0;
                    bool c1 = dc.y < dbest.y;
                    dbest.y = c1 ? dc.y : dbest.y;  jb1 = c1 ? j : jb1;
                } else {
                    dbest = __builtin_elementwise_min(dbest, dc);
                }
            }
        }
    }
    const size_t o0 = (size_t)chunk * nRowsTot + (size_t)b * nP;
    if (ARGMIN) {
        outPack[o0 + row0] = ((u64)__float_as_uint(dbest.x) << 32) | (unsigned)jb0;
        outPack[o0 + row1] = ((u64)__float_as_uint(dbest.y) << 32) | (unsigned)jb1;
    } else {
        outVal[o0 + row0] = __float_as_uint(dbest.x);
        outVal[o0 + row1] = __float_as_uint(dbest.y);
    }
}

// All four pairwise passes, one dispatch, 1152 blocks.
//  [0,   64)  coarse-rows : P=coarse(512), Q=tgt,    32 chunks x 2b, 1 tile
//  [64, 128)  coarse-cols : P=tgt(8192),  Q=coarse,  2 chunks x 16yb x 2b, 1 tile
//  [128, 640) fine-rows   : P=fine(8192), Q=tgt,  ARGMIN, 16 chunks x 16yb x 2b, 2 tiles
//  [640,1152) fine-cols   : P=tgt(8192),  Q=fine,         16 chunks x 16yb x 2b, 2 tiles
__global__ __launch_bounds__(TPB, 8) void pairmin_all(
    const float* __restrict__ coarse, const float* __restrict__ fine,
    const float* __restrict__ tgt,
    u64* __restrict__ pfr, unsigned* __restrict__ pfc,
    unsigned* __restrict__ pcr, unsigned* __restrict__ pcc,
    unsigned* __restrict__ counter)
{
    __shared__ float4 tile[TILE];
    const int bx = blockIdx.x;
    if (bx == 0 && threadIdx.x == 0) *counter = 0;   // init for tail_all
    if (bx < 64) {
        int chunk = bx & 31, b = bx >> 5;
        pairmin_body<false>(coarse, tgt, NC, MT, b, 0, chunk * TILE, 1,
                            chunk, B_ * NC, nullptr, pcr, tile);
    } else if (bx < 128) {
        int i = bx - 64;
        int chunk = i & 1, yb = (i >> 1) & 15, b = i >> 5;
        pairmin_body<false>(tgt, coarse, MT, NC, b, yb * RPB, chunk * TILE, 1,
                            chunk, B_ * MT, nullptr, pcc, tile);
    } else if (bx < 640) {
        int i = bx - 128;
        int chunk = i & 15, yb = (i >> 4) & 15, b = i >> 8;
        pairmin_body<true>(fine, tgt, NF, MT, b, yb * RPB, chunk * (MT / CF), 2,
                           chunk, B_ * NF, pfr, nullptr, tile);
    } else {
        int i = bx - 640;
        int chunk = i & 15, yb = (i >> 4) & 15, b = i >> 8;
        pairmin_body<false>(tgt, fine, MT, NF, b, yb * RPB, chunk * (NF / CF), 2,
                            chunk, B_ * MT, nullptr, pfc, tile);
    }
}

// ---------------------------------------------------------------------------
// tail_all: everything after the pairwise passes, one dispatch.
//  [0,  64) fine-rows: reduce 16 partials (u64 min = min d then min j), gather,
//           chamfer d1 sum, loss_ref/rot stats, wedge volumes (LDS halo).
//  [64,128) fine-cols value reduce -> d2f
//  [128,132) coarse-rows -> d1c
//  [132,196) coarse-cols -> d2c
// Each block writes its partial sums to bs[bx][16]; last-arriving block (via
// device-scope counter) reduces bs and writes the final scalar.
// ---------------------------------------------------------------------------
__global__ __launch_bounds__(TPB) void tail_all(
    const float* __restrict__ fine, const float* __restrict__ tgt,
    const u64* __restrict__ pfr, const unsigned* __restrict__ pfc,
    const unsigned* __restrict__ pcr, const unsigned* __restrict__ pcc,
    double* __restrict__ bs, unsigned* __restrict__ counter,
    float* __restrict__ out)
{
    __shared__ float sp[TPB + 2][3], yp[TPB + 2][3];
    __shared__ double redw[4][9];
    __shared__ double lred[4][13];
    __shared__ int lastflag;
    const int bx = blockIdx.x, tid = threadIdx.x;
    const int wave = tid >> 6, lane = tid & 63;

    double v_s = 0, v_d2f = 0, v_d1c = 0, v_d2c = 0, v_yd2 = 0, v_zs = 0, v_zt = 0;
    double vs = 0, vt = 0;
    int role_b = 0;

    if (bx < 64) {                              // ---- fine-rows ----
        const int base = bx * TPB;
        const int g = base + tid;
        const int b = base >> 13;  role_b = b;
        u64 best = pfr[g];
        #pragma unroll
        for (int c = 1; c < CF; ++c) {
            u64 p = pfr[(size_t)c * (B_ * NF) + g];
            best = p < best ? p : best;
        }
        float d1 = __uint_as_float((unsigned)(best >> 32));
        int idx  = (int)(best & 0xffffffffULL);
        float s = sqrtf(fmaxf(d1, 1e-12f));
        const float* y  = tgt  + ((size_t)b * MT + idx) * 3;
        const float* sr = fine + (size_t)g * 3;
        float y0 = y[0],  y1 = y[1],  y2 = y[2];
        float s0 = sr[0], s1 = sr[1], s2 = sr[2];
        yp[tid][0] = y0; yp[tid][1] = y1; yp[tid][2] = y2;
        sp[tid][0] = s0; sp[tid][1] = s1; sp[tid][2] = s2;
        const int base_b = base & (NF - 1);
        if (tid < 2 && base_b + TPB + tid < NF) {        // halo rows
            int g2 = base + TPB + tid;
            u64 b2 = pfr[g2];
            #pragma unroll
            for (int c = 1; c < CF; ++c) {
                u64 p = pfr[(size_t)c * (B_ * NF) + g2];
                b2 = p < b2 ? p : b2;
            }
            int i2 = (int)(b2 & 0xffffffffULL);
            const float* yh = tgt  + ((size_t)b * MT + i2) * 3;
            const float* sh = fine + (size_t)g2 * 3;
            #pragma unroll
            for (int k = 0; k < 3; ++k) { yp[TPB + tid][k] = yh[k]; sp[TPB + tid][k] = sh[k]; }
        }
        __syncthreads();
        v_s = s;
        float yd = s1 - y1;
        v_yd2 = (double)(yd * yd);
        v_zs  = (double)(s2 * s2);
        v_zt  = (double)(y2 * y2);
        int rb = base_b + tid;
        if (rb <= NF - 3) {          // same f32 exprs as the verified R3 kernel
            {
                const float* a = sp[tid]; const float* c = sp[tid+1]; const float* e = sp[tid+2];
                float c0 = a[1]*c[2] - a[2]*c[1];
                float c1 = a[2]*c[0] - a[0]*c[2];
                float c2 = a[0]*c[1] - a[1]*c[0];
                vs = (double)(c0*e[0] + c1*e[1] + c2*e[2]);
            }
            {
                const float* a = yp[tid]; const float* c = yp[tid+1]; const float* e = yp[tid+2];
                float c0 = a[1]*c[2] - a[2]*c[1];
                float c1 = a[2]*c[0] - a[0]*c[2];
                float c2 = a[0]*c[1] - a[1]*c[0];
                vt = (double)(c0*e[0] + c1*e[1] + c2*e[2]);
            }
        }
    } else if (bx < 128) {                      // ---- fine-cols ----
        const int g = (bx - 64) * TPB + tid;
        unsigned best = pfc[g];
        #pragma unroll
        for (int c = 1; c < CF; ++c) best = min(best, pfc[(size_t)c * (B_ * MT) + g]);
        v_d2f = (double)sqrtf(fmaxf(__uint_as_float(best), 1e-12f));
    } else if (bx < 132) {                      // ---- coarse-rows ----
        const int g = (bx - 128) * TPB + tid;
        unsigned best = pcr[g];
        #pragma unroll
        for (int c = 1; c < 32; ++c) best = min(best, pcr[(size_t)c * (B_ * NC) + g]);
        v_d1c = (double)sqrtf(fmaxf(__uint_as_float(best), 1e-12f));
    } else {                                    // ---- coarse-cols ----
        const int g = (bx - 132) * TPB + tid;
        unsigned best = min(pcc[g], pcc[(size_t)(B_ * MT) + g]);
        v_d2c = (double)sqrtf(fmaxf(__uint_as_float(best), 1e-12f));
    }

    // block reduce 9 values
    double r9[9] = {v_s, v_d2f, v_d1c, v_d2c, v_yd2, v_zs, v_zt, vs, vt};
    for (int o = 32; o; o >>= 1) {
        #pragma unroll
        for (int k = 0; k < 9; ++k) r9[k] += __shfl_down(r9[k], o);
    }
    if (lane == 0) {
        #pragma unroll
        for (int k = 0; k < 9; ++k) redw[wave][k] = r9[k];
    }
    __syncthreads();
    if (tid == 0) {
        double t9[9];
        #pragma unroll
        for (int k = 0; k < 9; ++k)
            t9[k] = redw[0][k] + redw[1][k] + redw[2][k] + redw[3][k];
        double* o = bs + (size_t)bx * 16;
        #pragma unroll
        for (int k = 0; k < 16; ++k) o[k] = 0.0;
        o[0] = t9[0]; o[1] = t9[1]; o[2] = t9[2]; o[3] = t9[3]; o[4] = t9[4];
        o[5 + role_b]  = t9[5];   // zs
        o[7 + role_b]  = t9[6];   // zt
        o[9 + role_b]  = t9[7];   // vs
        o[11 + role_b] = t9[8];   // vt
        __threadfence();
        unsigned old = atomicAdd(counter, 1u);
        lastflag = (old == TAIL_BLOCKS - 1);
    }
    __syncthreads();
    if (!lastflag) return;

    // ---- final combine (last block only) ----
    __threadfence();
    double c13[13];
    if (tid < TAIL_BLOCKS) {
        const double* p = bs + (size_t)tid * 16;
        #pragma unroll
        for (int k = 0; k < 13; ++k) c13[k] = p[k];
    } else {
        #pragma unroll
        for (int k = 0; k < 13; ++k) c13[k] = 0.0;
    }
    for (int o = 32; o; o >>= 1) {
        #pragma unroll
        for (int k = 0; k < 13; ++k) c13[k] += __shfl_down(c13[k], o);
    }
    if (lane == 0) {
        #pragma unroll
        for (int k = 0; k < 13; ++k) lred[wave][k] = c13[k];
    }
    __syncthreads();
    if (tid == 0) {
        double S[13];
        #pragma unroll
        for (int k = 0; k < 13; ++k)
            S[k] = lred[0][k] + lred[1][k] + lred[2][k] + lred[3][k];
        double m_d1f = S[0] / (double)(B_ * NF);
        double m_d2f = S[1] / (double)(B_ * MT);
        double m_d1c = S[2] / (double)(B_ * NC);
        double m_d2c = S[3] / (double)(B_ * MT);
        double loss_align_fine   = 0.5 * (m_d1f + m_d2f);
        double loss_align_coarse = 0.5 * (m_d1c + m_d2c);
        double loss_ref = S[4] / (double)(B_ * NF);
        double loss_rot = 0.0, loss_geo = 0.0;
        for (int b = 0; b < B_; ++b) {
            double dn = sqrt(S[5 + b]) - sqrt(S[7 + b]);
            loss_rot += dn * dn;
            double dv = (S[9 + b] - S[11 + b]) / 6.0;
            loss_geo += dv * dv;
        }
        loss_rot /= (double)B_;
        loss_geo /= (double)B_;
        out[0] = (float)(loss_rot + loss_ref + loss_align_coarse + loss_align_fine + loss_geo);
    }
}

extern "C" void kernel_launch(void* const* d_in, const int* in_sizes, int n_in,
                              void* d_out, int out_size, void* d_ws, size_t ws_size,
                              hipStream_t stream)
{
    const float* src_coarse = (const float*)d_in[0];
    const float* src_fine   = (const float*)d_in[1];
    const float* tgt        = (const float*)d_in[2];
    float* out = (float*)d_out;
    char*  ws  = (char*)d_ws;

    // ws layout (bytes), everything written before read — no init needed:
    //   [0,        2097152)  u64 pfr[16][16384]   fine-rows (d,j) partials
    //   [2097152,  3145728)  u32 pfc[16][16384]   fine-cols value partials
    //   [3145728,  3276800)  u32 pcr[32][1024]    coarse-rows value partials
    //   [3276800,  3407872)  u32 pcc[2][16384]    coarse-cols value partials
    //   [3407872,  3432960)  double bs[196][16]   per-tail-block sums
    //   [3432960,  3432964)  u32 counter          (zeroed by pairmin_all blk 0)
    u64*      pfr     = (u64*)(ws);
    unsigned* pfc     = (unsigned*)(ws + 2097152);
    unsigned* pcr     = (unsigned*)(ws + 3145728);
    unsigned* pcc     = (unsigned*)(ws + 3276800);
    double*   bs      = (double*)(ws + 3407872);
    unsigned* counter = (unsigned*)(ws + 3432960);

    pairmin_all<<<dim3(1152), TPB, 0, stream>>>(
        src_coarse, src_fine, tgt, pfr, pfc, pcr, pcc, counter);
    tail_all<<<dim3(TAIL_BLOCKS), TPB, 0, stream>>>(
        src_fine, tgt, pfr, pfc, pcr, pcc, bs, counter, out);
}